// Round 12
// baseline (128.089 us; speedup 1.0000x reference)
//
#include <hip/hip_runtime.h>

#define HW 50176            // 224*224
#define HW2 25088           // HW/2 (u32 = 2 f16 per frame)
#define HW4 12544           // HW/4
#define TT 64
#define NBP 784             // pass1 grid: 8 b × 98 hwb, 2 px/thread
#define SUMW 0.9999f        // 0.2989+0.587+0.114

__device__ __forceinline__ float gelu_erf(float x) {
    return 0.5f * x * (1.0f + erff(0.70710678f * x));
}
__device__ __forceinline__ float fast_rcp(float v) {
    float r; asm("v_rcp_f32 %0, %1" : "=v"(r) : "v"(v)); return r;
}
__device__ __forceinline__ float gelu_fast(float x) {
    // tanh-form gelu; max |err| ~3e-3 vs erf (cancels through normalize)
    float x2 = x * x;
    float e = exp2f(-x * fmaf(0.1029433f, x2, 2.3022078f));
    return x * fast_rcp(1.0f + e);
}
__device__ __forceinline__ unsigned encf(float f) {
    unsigned u = __float_as_uint(f);
    return (u & 0x80000000u) ? ~u : (u | 0x80000000u);
}
__device__ __forceinline__ float decf(unsigned u) {
    unsigned b = (u & 0x80000000u) ? (u ^ 0x80000000u) : ~u;
    return __uint_as_float(b);
}
__device__ __forceinline__ unsigned pk_min_f16(unsigned a, unsigned b) {
    unsigned r; asm("v_pk_min_f16 %0, %1, %2" : "=v"(r) : "v"(a), "v"(b)); return r;
}
__device__ __forceinline__ unsigned pack2(float lo, float hi) {
    auto p = __builtin_amdgcn_cvt_pkrtz(lo, hi);
    return __builtin_bit_cast(unsigned, p);
}
__device__ __forceinline__ unsigned pk2(float r) { return pack2(r, -r); }   // (r,-r)
__device__ __forceinline__ unsigned mm2(float2 r) { return pk_min_f16(pk2(r.x), pk2(r.y)); }

// Pass 1: identical to round 11 EXCEPT the prefetch pipeline is 2 frames deep
// (frame f issues at window f-7, consumed at f-4) to cover HBM latency at 3 waves/SIMD.
template<bool WGS>
__global__ __launch_bounds__(256, 4) void k_pass1(const float* __restrict__ x,
                                                  unsigned* __restrict__ part,
                                                  unsigned* __restrict__ gs) {
    __shared__ unsigned smin[TT], smax[TT];
    const int tid = threadIdx.x;
    if (tid < TT) smin[tid] = 0xFFFFFFFFu;
    else if (tid < 2 * TT) smax[tid - TT] = 0u;
    __syncthreads();

    const int bid = blockIdx.x;            // < 784 = 8 b × 98 hwb
    const int b   = bid / 98;
    const int hwb = bid - b * 98;
    const int hw  = (hwb * 256 + tid) * 2;
    const float* xa = x + ((size_t)(b * 3 + 0) * TT) * (size_t)HW + hw;
    const float* xb = x + ((size_t)(b * 3 + 1) * TT) * (size_t)HW + hw;
    const float* xc = x + ((size_t)(b * 3 + 2) * TT) * (size_t)HW + hw;
    unsigned* gp = gs + ((size_t)b * TT) * (size_t)HW2 + (hwb * 256 + tid);

    const int lane = tid & 63;
    unsigned keep = 0x7BFF7BFFu;           // lane L ends up holding window t=L

    // frames t..t+4 in a0..a4; pa = t+5, qa = t+6; pointers -> t+7
    float2 a0 = *(const float2*)xa, b0 = *(const float2*)xb, c0 = *(const float2*)xc;
    float2 a1 = *(const float2*)(xa + HW), b1 = *(const float2*)(xb + HW), c1 = *(const float2*)(xc + HW);
    float2 a2 = *(const float2*)(xa + 2*(size_t)HW), b2 = *(const float2*)(xb + 2*(size_t)HW), c2 = *(const float2*)(xc + 2*(size_t)HW);
    float2 a3 = *(const float2*)(xa + 3*(size_t)HW), b3 = *(const float2*)(xb + 3*(size_t)HW), c3 = *(const float2*)(xc + 3*(size_t)HW);
    float2 a4 = *(const float2*)(xa + 4*(size_t)HW), b4 = *(const float2*)(xb + 4*(size_t)HW), c4 = *(const float2*)(xc + 4*(size_t)HW);
    float2 pa = *(const float2*)(xa + 5*(size_t)HW), pb = *(const float2*)(xb + 5*(size_t)HW), pc = *(const float2*)(xc + 5*(size_t)HW);
    float2 qa = *(const float2*)(xa + 6*(size_t)HW), qb = *(const float2*)(xb + 6*(size_t)HW), qc = *(const float2*)(xc + 6*(size_t)HW);
    xa += 7 * (size_t)HW; xb += 7 * (size_t)HW; xc += 7 * (size_t)HW;

    unsigned acc[8];

    #define STEP_FULL(J) { \
        float2 ra, rb, rc; \
        ra.x = fmaf(4.f, a4.x - a0.x, 2.f * (a3.x - a1.x)); ra.y = fmaf(4.f, a4.y - a0.y, 2.f * (a3.y - a1.y)); \
        rb.x = fmaf(4.f, b4.x - b0.x, 2.f * (b3.x - b1.x)); rb.y = fmaf(4.f, b4.y - b0.y, 2.f * (b3.y - b1.y)); \
        rc.x = fmaf(4.f, c4.x - c0.x, 2.f * (c3.x - c1.x)); rc.y = fmaf(4.f, c4.y - c0.y, 2.f * (c3.y - c1.y)); \
        acc[J] = pk_min_f16(acc[J], pk_min_f16(pk_min_f16(mm2(ra), mm2(rb)), mm2(rc))); \
        if constexpr (WGS) { \
            float gx = fmaf(0.114f, gelu_fast(rc.x), fmaf(0.587f, gelu_fast(rb.x), 0.2989f * gelu_fast(ra.x))); \
            float gy = fmaf(0.114f, gelu_fast(rc.y), fmaf(0.587f, gelu_fast(rb.y), 0.2989f * gelu_fast(ra.y))); \
            *gp = pack2(gx, gy); \
        } \
        gp += HW2; \
        a0 = a1; a1 = a2; a2 = a3; a3 = a4; a4 = pa; pa = qa; \
        b0 = b1; b1 = b2; b2 = b3; b3 = b4; b4 = pb; pb = qb; \
        c0 = c1; c1 = c2; c2 = c3; c3 = c4; c4 = pc; pc = qc; }

    #define PREFETCH() { qa = *(const float2*)xa; qb = *(const float2*)xb; qc = *(const float2*)xc; \
                         xa += HW; xb += HW; xc += HW; }

    #define FLUSH(J, T) { unsigned v = acc[J]; \
        v = pk_min_f16(v, (unsigned)__shfl_xor((int)v, 32, 64)); \
        v = pk_min_f16(v, (unsigned)__shfl_xor((int)v, 16, 64)); \
        v = pk_min_f16(v, (unsigned)__shfl_xor((int)v,  8, 64)); \
        v = pk_min_f16(v, (unsigned)__shfl_xor((int)v,  4, 64)); \
        v = pk_min_f16(v, (unsigned)__shfl_xor((int)v,  2, 64)); \
        v = pk_min_f16(v, (unsigned)__shfl_xor((int)v,  1, 64)); \
        if (lane == (T)) keep = v; }

    // ---- groups g=0..6 cover t=0..55 (prefetch t+7 = frames 7..62) ----
    for (int g = 0; g < 7; ++g) {
        #pragma unroll
        for (int j = 0; j < 8; ++j) acc[j] = 0x7BFF7BFFu;
        #pragma unroll
        for (int j = 0; j < 8; ++j) {
            STEP_FULL(j)
            PREFETCH()
        }
        #pragma unroll
        for (int j = 0; j < 8; ++j) FLUSH(j, g * 8 + j)
    }

    {   // peeled final group: t=56..63 (entry: a=56..60, pa=61, qa=62, ptr->63)
        #pragma unroll
        for (int j = 0; j < 8; ++j) acc[j] = 0x7BFF7BFFu;
        STEP_FULL(0) PREFETCH()             // t=56; load frame 63
        STEP_FULL(1)                        // t=57
        STEP_FULL(2)                        // t=58
        STEP_FULL(3)                        // t=59 -> a0..a3 = 60..63
        {   // t=60: weights -3,-1,1,3
            float2 ra, rb, rc;
            ra.x = fmaf(3.f, a3.x - a0.x, a2.x - a1.x); ra.y = fmaf(3.f, a3.y - a0.y, a2.y - a1.y);
            rb.x = fmaf(3.f, b3.x - b0.x, b2.x - b1.x); rb.y = fmaf(3.f, b3.y - b0.y, b2.y - b1.y);
            rc.x = fmaf(3.f, c3.x - c0.x, c2.x - c1.x); rc.y = fmaf(3.f, c3.y - c0.y, c2.y - c1.y);
            acc[4] = pk_min_f16(acc[4], pk_min_f16(pk_min_f16(mm2(ra), mm2(rb)), mm2(rc)));
            if constexpr (WGS) {
                float gx = fmaf(0.114f, gelu_fast(rc.x), fmaf(0.587f, gelu_fast(rb.x), 0.2989f * gelu_fast(ra.x)));
                float gy = fmaf(0.114f, gelu_fast(rc.y), fmaf(0.587f, gelu_fast(rb.y), 0.2989f * gelu_fast(ra.y)));
                *gp = pack2(gx, gy);
            }
            gp += HW2;
            a0 = a1; a1 = a2; a2 = a3;
            b0 = b1; b1 = b2; b2 = b3;
            c0 = c1; c1 = c2; c2 = c3;
        }
        {   // t=61: weights -2,0,2
            float2 ra, rb, rc;
            ra.x = 2.f*(a2.x-a0.x); ra.y = 2.f*(a2.y-a0.y);
            rb.x = 2.f*(b2.x-b0.x); rb.y = 2.f*(b2.y-b0.y);
            rc.x = 2.f*(c2.x-c0.x); rc.y = 2.f*(c2.y-c0.y);
            acc[5] = pk_min_f16(acc[5], pk_min_f16(pk_min_f16(mm2(ra), mm2(rb)), mm2(rc)));
            if constexpr (WGS) {
                float gx = fmaf(0.114f, gelu_fast(rc.x), fmaf(0.587f, gelu_fast(rb.x), 0.2989f * gelu_fast(ra.x)));
                float gy = fmaf(0.114f, gelu_fast(rc.y), fmaf(0.587f, gelu_fast(rb.y), 0.2989f * gelu_fast(ra.y)));
                *gp = pack2(gx, gy);
            }
            gp += HW2;
            a0 = a1; a1 = a2;
            b0 = b1; b1 = b2;
            c0 = c1; c1 = c2;
        }
        {   // t=62: weights -1,1
            float2 ra, rb, rc;
            ra.x = a1.x-a0.x; ra.y = a1.y-a0.y;
            rb.x = b1.x-b0.x; rb.y = b1.y-b0.y;
            rc.x = c1.x-c0.x; rc.y = c1.y-c0.y;
            acc[6] = pk_min_f16(acc[6], pk_min_f16(pk_min_f16(mm2(ra), mm2(rb)), mm2(rc)));
            if constexpr (WGS) {
                float gx = fmaf(0.114f, gelu_fast(rc.x), fmaf(0.587f, gelu_fast(rb.x), 0.2989f * gelu_fast(ra.x)));
                float gy = fmaf(0.114f, gelu_fast(rc.y), fmaf(0.587f, gelu_fast(rb.y), 0.2989f * gelu_fast(ra.y)));
                *gp = pack2(gx, gy);
            }
            gp += HW2;
        }
        {   // t=63: weight 0 -> re = 0, gs = 0
            acc[7] = pk_min_f16(acc[7], 0u);
            if constexpr (WGS) *gp = 0u;
        }
        #pragma unroll
        for (int j = 0; j < 8; ++j) FLUSH(j, 56 + j)
    }
    #undef STEP_FULL
    #undef PREFETCH
    #undef FLUSH

    {   // lane L holds window t=L: tail gelu eval + LDS reduce
        union { unsigned u; _Float16 h[2]; } cv; cv.u = keep;
        const float amin = (float)cv.h[0];
        const float amax = -(float)cv.h[1];
        const float g0 = gelu_erf(amin), g1 = gelu_erf(amax);
        const float gmax = fmaxf(g0, g1);
        const float XSTAR = -0.7517916f;
        float gmin;
        if (amin >= XSTAR)      gmin = g0;
        else if (amax <= XSTAR) gmin = g1;
        else                    gmin = fminf(gelu_erf(XSTAR), fminf(g0, g1));
        atomicMin(&smin[lane], encf(gmin));
        atomicMax(&smax[lane], encf(gmax));
    }
    __syncthreads();
    // per-block partial store (transposed: row over t, column = bid)
    if (tid < TT)            part[(size_t)tid * NBP + bid] = smin[tid];
    else if (tid < 2 * TT)   part[(size_t)tid * NBP + bid] = smax[tid - TT];
}

// block-wide reduce of partial rows tm (min) and 64+tm (max)
__device__ __forceinline__ void reduce_part(const unsigned* __restrict__ part, int tm,
                                            int tid, float& A, float& Bv) {
    __shared__ unsigned rm[4], rx[4];
    const unsigned* pm = part + (size_t)tm * NBP;
    const unsigned* px = part + (size_t)(TT + tm) * NBP;
    unsigned vmn = 0xFFFFFFFFu, vmx = 0u;
    for (int i = tid; i < NBP; i += 256) {
        vmn = min(vmn, pm[i]);
        vmx = max(vmx, px[i]);
    }
    #pragma unroll
    for (int off = 32; off; off >>= 1) {
        vmn = min(vmn, (unsigned)__shfl_xor((int)vmn, off, 64));
        vmx = max(vmx, (unsigned)__shfl_xor((int)vmx, off, 64));
    }
    if ((tid & 63) == 0) { rm[tid >> 6] = vmn; rx[tid >> 6] = vmx; }
    __syncthreads();
    vmn = min(min(rm[0], rm[1]), min(rm[2], rm[3]));
    vmx = max(max(rx[0], rx[1]), max(rx[2], rx[3]));
    float mn = decf(vmn);
    float mx = decf(vmx) - mn;
    float inv = fast_rcp((mx != 0.f) ? mx : 1e-5f);
    A  = inv;
    Bv = -mn * SUMW * inv;
}

// Pass 3: out[b,t] = (t<4) ? 0 : gs[b,t-4]*A + B; A/B reduced from partials inline.
__global__ __launch_bounds__(256) void k_pass3(const unsigned* __restrict__ gs,
                                               const unsigned* __restrict__ part,
                                               float* __restrict__ out) {
    const int bid = blockIdx.x;
    const int b   = bid / 476;             // 476 = 68*7
    const int r   = bid - b * 476;
    const int t   = r / 7;
    const int seg = r - t * 7;
    const int tid = threadIdx.x;
    const int base4 = seg * 1792 + tid;    // float4 index within frame
    float4* op = (float4*)out + ((size_t)b * 68 + t) * HW4 + base4;

    if (t < 4) {
        float4 z = make_float4(0.f, 0.f, 0.f, 0.f);
        #pragma unroll
        for (int k = 0; k < 7; ++k) op[k * 256] = z;
        return;
    }
    const int tm = t - 4;
    float A, Bv;
    reduce_part(part, tm, tid, A, Bv);

    const uint2* gpp = (const uint2*)gs + ((size_t)b * TT + tm) * HW4 + base4;
    #pragma unroll
    for (int k = 0; k < 7; ++k) {
        uint2 v = gpp[k * 256];
        union { unsigned u; _Float16 h[2]; } lo, hi; lo.u = v.x; hi.u = v.y;
        float4 o;
        o.x = fmaf((float)lo.h[0], A, Bv);
        o.y = fmaf((float)lo.h[1], A, Bv);
        o.z = fmaf((float)hi.h[0], A, Bv);
        o.w = fmaf((float)hi.h[1], A, Bv);
        op[k * 256] = o;
    }
}

// Fallback helpers (ws too small for gs): consts kernel + direct erf pass
__global__ __launch_bounds__(256) void k_consts(const unsigned* __restrict__ part,
                                                float* __restrict__ ab) {
    const int t = blockIdx.x;              // 64 blocks, one per t
    float A, Bv;
    reduce_part(part, t, threadIdx.x, A, Bv);
    if (threadIdx.x == 0) { ab[t] = A; ab[TT + t] = Bv; }
}

__global__ __launch_bounds__(256) void k_pass2_direct(const float* __restrict__ x,
                                                      const float* __restrict__ ab,
                                                      float* __restrict__ out) {
    __shared__ float sA[TT], sB[TT];
    const int tid = threadIdx.x;
    if (tid < TT)          sA[tid] = ab[tid];
    else if (tid < 2 * TT) sB[tid - TT] = ab[tid];
    __syncthreads();

    const int pix = blockIdx.x * 256 + tid;
    const int b  = pix / HW;
    const int hw = pix - b * HW;
    const float* x0 = x + (size_t)(b * 3) * (TT * (size_t)HW) + hw;
    const float* x1 = x0 + (size_t)TT * HW;
    const float* x2 = x1 + (size_t)TT * HW;
    float* op = out + (size_t)b * (68 * (size_t)HW) + hw;

    op[0] = 0.f; op[HW] = 0.f; op[2 * (size_t)HW] = 0.f; op[3 * (size_t)HW] = 0.f;
    op += 4 * (size_t)HW;

    float a0 = x0[0], a1 = x0[HW], a2 = x0[2*HW], a3 = x0[3*HW], a4 = x0[4*HW];
    float b0 = x1[0], b1 = x1[HW], b2 = x1[2*HW], b3 = x1[3*HW], b4 = x1[4*HW];
    float c0 = x2[0], c1 = x2[HW], c2 = x2[2*HW], c3 = x2[3*HW], c4 = x2[4*HW];

    auto emit = [&](int t, float ra, float rb, float rc) {
        float gsv = 0.2989f * gelu_erf(ra) + 0.587f * gelu_erf(rb) + 0.114f * gelu_erf(rc);
        op[(size_t)t * HW] = fmaf(gsv, sA[t], sB[t]);
    };

    for (int t = 0; t < 59; ++t) {
        emit(t, 4.f*(a4-a0) + 2.f*(a3-a1), 4.f*(b4-b0) + 2.f*(b3-b1), 4.f*(c4-c0) + 2.f*(c3-c1));
        a0=a1; a1=a2; a2=a3; a3=a4; a4 = x0[(size_t)(t+5)*HW];
        b0=b1; b1=b2; b2=b3; b3=b4; b4 = x1[(size_t)(t+5)*HW];
        c0=c1; c1=c2; c2=c3; c3=c4; c4 = x2[(size_t)(t+5)*HW];
    }
    emit(59, 4.f*(a4-a0) + 2.f*(a3-a1), 4.f*(b4-b0) + 2.f*(b3-b1), 4.f*(c4-c0) + 2.f*(c3-c1));
    a0=a1; a1=a2; a2=a3; a3=a4; b0=b1; b1=b2; b2=b3; b3=b4; c0=c1; c1=c2; c2=c3; c3=c4;
    emit(60, 3.f*(a3-a0) + (a2-a1), 3.f*(b3-b0) + (b2-b1), 3.f*(c3-c0) + (c2-c1));
    a0=a1; a1=a2; a2=a3; b0=b1; b1=b2; b2=b3; c0=c1; c1=c2; c2=c3;
    emit(61, 2.f*(a2-a0), 2.f*(b2-b0), 2.f*(c2-c0));
    a0=a1; a1=a2; b0=b1; b1=b2; c0=c1; c1=c2;
    emit(62, a1-a0, b1-b0, c1-c0);
    op[63 * (size_t)HW] = sB[63];
}

extern "C" void kernel_launch(void* const* d_in, const int* in_sizes, int n_in,
                              void* d_out, int out_size, void* d_ws, size_t ws_size,
                              hipStream_t stream) {
    const float* x = (const float*)d_in[0];
    float* out = (float*)d_out;
    // ws layout: [0,1024): ab (fallback); [1024, +401408): part; then gs (~51.4MB)
    float* ab = (float*)d_ws;
    unsigned* part = (unsigned*)((char*)d_ws + 1024);
    const size_t part_bytes = (size_t)2 * TT * NBP * 4;           // 401408
    unsigned* gs = (unsigned*)((char*)d_ws + 1024 + part_bytes);
    const size_t need = 1024 + part_bytes + (size_t)8 * TT * (size_t)HW2 * 4;  // ~51.8 MB

    if (ws_size >= need) {
        k_pass1<true><<<NBP, 256, 0, stream>>>(x, part, gs);
        k_pass3<<<3808, 256, 0, stream>>>(gs, part, out);
    } else if (ws_size >= 1024 + part_bytes) {
        k_pass1<false><<<NBP, 256, 0, stream>>>(x, part, nullptr);
        k_consts<<<TT, 256, 0, stream>>>(part, ab);
        k_pass2_direct<<<1568, 256, 0, stream>>>(x, ab, out);
    }
}

// Round 13
// 125.449 us; speedup vs baseline: 1.0210x; 1.0210x over previous
//
#include <hip/hip_runtime.h>

#define HW 50176            // 224*224
#define HW2 25088           // HW/2 (u32 = 2 f16 per frame)
#define HW4 12544           // HW/4
#define TT 64
#define NBP 1568            // pass1 grid: 8 b × 196 hwb, 128 thr, 2 px/thread
#define SUMW 0.9999f        // 0.2989+0.587+0.114

__device__ __forceinline__ float gelu_erf(float x) {
    return 0.5f * x * (1.0f + erff(0.70710678f * x));
}
__device__ __forceinline__ float fast_rcp(float v) {
    float r; asm("v_rcp_f32 %0, %1" : "=v"(r) : "v"(v)); return r;
}
__device__ __forceinline__ float gelu_fast(float x) {
    // tanh-form gelu; max |err| ~3e-3 vs erf (cancels through normalize)
    float x2 = x * x;
    float e = exp2f(-x * fmaf(0.1029433f, x2, 2.3022078f));
    return x * fast_rcp(1.0f + e);
}
__device__ __forceinline__ unsigned encf(float f) {
    unsigned u = __float_as_uint(f);
    return (u & 0x80000000u) ? ~u : (u | 0x80000000u);
}
__device__ __forceinline__ float decf(unsigned u) {
    unsigned b = (u & 0x80000000u) ? (u ^ 0x80000000u) : ~u;
    return __uint_as_float(b);
}
__device__ __forceinline__ unsigned pk_min_f16(unsigned a, unsigned b) {
    unsigned r; asm("v_pk_min_f16 %0, %1, %2" : "=v"(r) : "v"(a), "v"(b)); return r;
}
__device__ __forceinline__ unsigned pack2(float lo, float hi) {
    auto p = __builtin_amdgcn_cvt_pkrtz(lo, hi);
    return __builtin_bit_cast(unsigned, p);
}
__device__ __forceinline__ unsigned pk2(float r) { return pack2(r, -r); }   // (r,-r)
__device__ __forceinline__ unsigned mm2(float2 r) { return pk_min_f16(pk2(r.x), pk2(r.y)); }

// Pass 1: round-11 body, but 128-thread blocks / grid 1568 (6.125 blocks/CU)
// to cut per-CU load imbalance from 4/3 to 7/6.
template<bool WGS>
__global__ __launch_bounds__(128, 4) void k_pass1(const float* __restrict__ x,
                                                  unsigned* __restrict__ part,
                                                  unsigned* __restrict__ gs) {
    __shared__ unsigned smin[TT], smax[TT];
    const int tid = threadIdx.x;
    if (tid < TT) smin[tid] = 0xFFFFFFFFu;
    else smax[tid - TT] = 0u;
    __syncthreads();

    const int bid = blockIdx.x;            // < 1568 = 8 b × 196 hwb
    const int b   = bid / 196;
    const int hwb = bid - b * 196;
    const int hw  = (hwb * 128 + tid) * 2;
    const float* xa = x + ((size_t)(b * 3 + 0) * TT) * (size_t)HW + hw;
    const float* xb = x + ((size_t)(b * 3 + 1) * TT) * (size_t)HW + hw;
    const float* xc = x + ((size_t)(b * 3 + 2) * TT) * (size_t)HW + hw;
    unsigned* gp = gs + ((size_t)b * TT) * (size_t)HW2 + (hwb * 128 + tid);

    const int lane = tid & 63;
    unsigned keep = 0x7BFF7BFFu;           // lane L ends up holding window t=L

    float2 a0 = *(const float2*)xa, b0 = *(const float2*)xb, c0 = *(const float2*)xc;
    float2 a1 = *(const float2*)(xa + HW), b1 = *(const float2*)(xb + HW), c1 = *(const float2*)(xc + HW);
    float2 a2 = *(const float2*)(xa + 2*(size_t)HW), b2 = *(const float2*)(xb + 2*(size_t)HW), c2 = *(const float2*)(xc + 2*(size_t)HW);
    float2 a3 = *(const float2*)(xa + 3*(size_t)HW), b3 = *(const float2*)(xb + 3*(size_t)HW), c3 = *(const float2*)(xc + 3*(size_t)HW);
    float2 a4 = *(const float2*)(xa + 4*(size_t)HW), b4 = *(const float2*)(xb + 4*(size_t)HW), c4 = *(const float2*)(xc + 4*(size_t)HW);
    float2 pa = *(const float2*)(xa + 5*(size_t)HW), pb = *(const float2*)(xb + 5*(size_t)HW), pc = *(const float2*)(xc + 5*(size_t)HW);
    xa += 6 * (size_t)HW; xb += 6 * (size_t)HW; xc += 6 * (size_t)HW;

    unsigned acc[8];

    #define STEP_FULL(J) { \
        float2 ra, rb, rc; \
        ra.x = fmaf(4.f, a4.x - a0.x, 2.f * (a3.x - a1.x)); ra.y = fmaf(4.f, a4.y - a0.y, 2.f * (a3.y - a1.y)); \
        rb.x = fmaf(4.f, b4.x - b0.x, 2.f * (b3.x - b1.x)); rb.y = fmaf(4.f, b4.y - b0.y, 2.f * (b3.y - b1.y)); \
        rc.x = fmaf(4.f, c4.x - c0.x, 2.f * (c3.x - c1.x)); rc.y = fmaf(4.f, c4.y - c0.y, 2.f * (c3.y - c1.y)); \
        acc[J] = pk_min_f16(acc[J], pk_min_f16(pk_min_f16(mm2(ra), mm2(rb)), mm2(rc))); \
        if constexpr (WGS) { \
            float gx = fmaf(0.114f, gelu_fast(rc.x), fmaf(0.587f, gelu_fast(rb.x), 0.2989f * gelu_fast(ra.x))); \
            float gy = fmaf(0.114f, gelu_fast(rc.y), fmaf(0.587f, gelu_fast(rb.y), 0.2989f * gelu_fast(ra.y))); \
            *gp = pack2(gx, gy); \
        } \
        gp += HW2; \
        a0 = a1; a1 = a2; a2 = a3; a3 = a4; a4 = pa; \
        b0 = b1; b1 = b2; b2 = b3; b3 = b4; b4 = pb; \
        c0 = c1; c1 = c2; c2 = c3; c3 = c4; c4 = pc; }

    #define PREFETCH() { pa = *(const float2*)xa; pb = *(const float2*)xb; pc = *(const float2*)xc; \
                         xa += HW; xb += HW; xc += HW; }

    #define FLUSH(J, T) { unsigned v = acc[J]; \
        v = pk_min_f16(v, (unsigned)__shfl_xor((int)v, 32, 64)); \
        v = pk_min_f16(v, (unsigned)__shfl_xor((int)v, 16, 64)); \
        v = pk_min_f16(v, (unsigned)__shfl_xor((int)v,  8, 64)); \
        v = pk_min_f16(v, (unsigned)__shfl_xor((int)v,  4, 64)); \
        v = pk_min_f16(v, (unsigned)__shfl_xor((int)v,  2, 64)); \
        v = pk_min_f16(v, (unsigned)__shfl_xor((int)v,  1, 64)); \
        if (lane == (T)) keep = v; }

    // ---- groups g=0..6 cover t=0..55 ----
    for (int g = 0; g < 7; ++g) {
        #pragma unroll
        for (int j = 0; j < 8; ++j) acc[j] = 0x7BFF7BFFu;
        #pragma unroll
        for (int j = 0; j < 8; ++j) {
            STEP_FULL(j)
            PREFETCH()                      // frame t+6 <= 61, always valid
        }
        #pragma unroll
        for (int j = 0; j < 8; ++j) FLUSH(j, g * 8 + j)
    }

    {   // peeled final group: t=56..63 (entry: a=56..60, pa=61, ptr->62)
        #pragma unroll
        for (int j = 0; j < 8; ++j) acc[j] = 0x7BFF7BFFu;
        STEP_FULL(0) PREFETCH()             // t=56, load 62
        STEP_FULL(1) PREFETCH()             // t=57, load 63
        STEP_FULL(2)                        // t=58
        STEP_FULL(3)                        // t=59 -> a0..a3 = 60..63
        {   // t=60: weights -3,-1,1,3
            float2 ra, rb, rc;
            ra.x = fmaf(3.f, a3.x - a0.x, a2.x - a1.x); ra.y = fmaf(3.f, a3.y - a0.y, a2.y - a1.y);
            rb.x = fmaf(3.f, b3.x - b0.x, b2.x - b1.x); rb.y = fmaf(3.f, b3.y - b0.y, b2.y - b1.y);
            rc.x = fmaf(3.f, c3.x - c0.x, c2.x - c1.x); rc.y = fmaf(3.f, c3.y - c0.y, c2.y - c1.y);
            acc[4] = pk_min_f16(acc[4], pk_min_f16(pk_min_f16(mm2(ra), mm2(rb)), mm2(rc)));
            if constexpr (WGS) {
                float gx = fmaf(0.114f, gelu_fast(rc.x), fmaf(0.587f, gelu_fast(rb.x), 0.2989f * gelu_fast(ra.x)));
                float gy = fmaf(0.114f, gelu_fast(rc.y), fmaf(0.587f, gelu_fast(rb.y), 0.2989f * gelu_fast(ra.y)));
                *gp = pack2(gx, gy);
            }
            gp += HW2;
            a0 = a1; a1 = a2; a2 = a3;
            b0 = b1; b1 = b2; b2 = b3;
            c0 = c1; c1 = c2; c2 = c3;
        }
        {   // t=61: weights -2,0,2
            float2 ra, rb, rc;
            ra.x = 2.f*(a2.x-a0.x); ra.y = 2.f*(a2.y-a0.y);
            rb.x = 2.f*(b2.x-b0.x); rb.y = 2.f*(b2.y-b0.y);
            rc.x = 2.f*(c2.x-c0.x); rc.y = 2.f*(c2.y-c0.y);
            acc[5] = pk_min_f16(acc[5], pk_min_f16(pk_min_f16(mm2(ra), mm2(rb)), mm2(rc)));
            if constexpr (WGS) {
                float gx = fmaf(0.114f, gelu_fast(rc.x), fmaf(0.587f, gelu_fast(rb.x), 0.2989f * gelu_fast(ra.x)));
                float gy = fmaf(0.114f, gelu_fast(rc.y), fmaf(0.587f, gelu_fast(rb.y), 0.2989f * gelu_fast(ra.y)));
                *gp = pack2(gx, gy);
            }
            gp += HW2;
            a0 = a1; a1 = a2;
            b0 = b1; b1 = b2;
            c0 = c1; c1 = c2;
        }
        {   // t=62: weights -1,1
            float2 ra, rb, rc;
            ra.x = a1.x-a0.x; ra.y = a1.y-a0.y;
            rb.x = b1.x-b0.x; rb.y = b1.y-b0.y;
            rc.x = c1.x-c0.x; rc.y = c1.y-c0.y;
            acc[6] = pk_min_f16(acc[6], pk_min_f16(pk_min_f16(mm2(ra), mm2(rb)), mm2(rc)));
            if constexpr (WGS) {
                float gx = fmaf(0.114f, gelu_fast(rc.x), fmaf(0.587f, gelu_fast(rb.x), 0.2989f * gelu_fast(ra.x)));
                float gy = fmaf(0.114f, gelu_fast(rc.y), fmaf(0.587f, gelu_fast(rb.y), 0.2989f * gelu_fast(ra.y)));
                *gp = pack2(gx, gy);
            }
            gp += HW2;
        }
        {   // t=63: weight 0 -> re = 0, gs = 0
            acc[7] = pk_min_f16(acc[7], 0u);
            if constexpr (WGS) *gp = 0u;
        }
        #pragma unroll
        for (int j = 0; j < 8; ++j) FLUSH(j, 56 + j)
    }
    #undef STEP_FULL
    #undef PREFETCH
    #undef FLUSH

    {   // lane L holds window t=L: tail gelu eval + LDS reduce
        union { unsigned u; _Float16 h[2]; } cv; cv.u = keep;
        const float amin = (float)cv.h[0];
        const float amax = -(float)cv.h[1];
        const float g0 = gelu_erf(amin), g1 = gelu_erf(amax);
        const float gmax = fmaxf(g0, g1);
        const float XSTAR = -0.7517916f;
        float gmin;
        if (amin >= XSTAR)      gmin = g0;
        else if (amax <= XSTAR) gmin = g1;
        else                    gmin = fminf(gelu_erf(XSTAR), fminf(g0, g1));
        atomicMin(&smin[lane], encf(gmin));
        atomicMax(&smax[lane], encf(gmax));
    }
    __syncthreads();
    // per-block partial store (transposed: row over t, column = bid)
    if (tid < TT)            part[(size_t)tid * NBP + bid] = smin[tid];
    else                     part[(size_t)tid * NBP + bid] = smax[tid - TT];
}

// block-wide reduce (256-thread callers) of partial rows tm (min) and 64+tm (max)
__device__ __forceinline__ void reduce_part(const unsigned* __restrict__ part, int tm,
                                            int tid, float& A, float& Bv) {
    __shared__ unsigned rm[4], rx[4];
    const unsigned* pm = part + (size_t)tm * NBP;
    const unsigned* px = part + (size_t)(TT + tm) * NBP;
    unsigned vmn = 0xFFFFFFFFu, vmx = 0u;
    for (int i = tid; i < NBP; i += 256) {
        vmn = min(vmn, pm[i]);
        vmx = max(vmx, px[i]);
    }
    #pragma unroll
    for (int off = 32; off; off >>= 1) {
        vmn = min(vmn, (unsigned)__shfl_xor((int)vmn, off, 64));
        vmx = max(vmx, (unsigned)__shfl_xor((int)vmx, off, 64));
    }
    if ((tid & 63) == 0) { rm[tid >> 6] = vmn; rx[tid >> 6] = vmx; }
    __syncthreads();
    vmn = min(min(rm[0], rm[1]), min(rm[2], rm[3]));
    vmx = max(max(rx[0], rx[1]), max(rx[2], rx[3]));
    float mn = decf(vmn);
    float mx = decf(vmx) - mn;
    float inv = fast_rcp((mx != 0.f) ? mx : 1e-5f);
    A  = inv;
    Bv = -mn * SUMW * inv;
}

// Pass 3: out[b,t] = (t<4) ? 0 : gs[b,t-4]*A + B; A/B reduced from partials inline.
__global__ __launch_bounds__(256) void k_pass3(const unsigned* __restrict__ gs,
                                               const unsigned* __restrict__ part,
                                               float* __restrict__ out) {
    const int bid = blockIdx.x;
    const int b   = bid / 476;             // 476 = 68*7
    const int r   = bid - b * 476;
    const int t   = r / 7;
    const int seg = r - t * 7;
    const int tid = threadIdx.x;
    const int base4 = seg * 1792 + tid;    // float4 index within frame
    float4* op = (float4*)out + ((size_t)b * 68 + t) * HW4 + base4;

    if (t < 4) {
        float4 z = make_float4(0.f, 0.f, 0.f, 0.f);
        #pragma unroll
        for (int k = 0; k < 7; ++k) op[k * 256] = z;
        return;
    }
    const int tm = t - 4;
    float A, Bv;
    reduce_part(part, tm, tid, A, Bv);

    const uint2* gpp = (const uint2*)gs + ((size_t)b * TT + tm) * HW4 + base4;
    #pragma unroll
    for (int k = 0; k < 7; ++k) {
        uint2 v = gpp[k * 256];
        union { unsigned u; _Float16 h[2]; } lo, hi; lo.u = v.x; hi.u = v.y;
        float4 o;
        o.x = fmaf((float)lo.h[0], A, Bv);
        o.y = fmaf((float)lo.h[1], A, Bv);
        o.z = fmaf((float)hi.h[0], A, Bv);
        o.w = fmaf((float)hi.h[1], A, Bv);
        op[k * 256] = o;
    }
}

// Fallback helpers (ws too small for gs): consts kernel + direct erf pass
__global__ __launch_bounds__(256) void k_consts(const unsigned* __restrict__ part,
                                                float* __restrict__ ab) {
    const int t = blockIdx.x;              // 64 blocks, one per t
    float A, Bv;
    reduce_part(part, t, threadIdx.x, A, Bv);
    if (threadIdx.x == 0) { ab[t] = A; ab[TT + t] = Bv; }
}

__global__ __launch_bounds__(256) void k_pass2_direct(const float* __restrict__ x,
                                                      const float* __restrict__ ab,
                                                      float* __restrict__ out) {
    __shared__ float sA[TT], sB[TT];
    const int tid = threadIdx.x;
    if (tid < TT)          sA[tid] = ab[tid];
    else if (tid < 2 * TT) sB[tid - TT] = ab[tid];
    __syncthreads();

    const int pix = blockIdx.x * 256 + tid;
    const int b  = pix / HW;
    const int hw = pix - b * HW;
    const float* x0 = x + (size_t)(b * 3) * (TT * (size_t)HW) + hw;
    const float* x1 = x0 + (size_t)TT * HW;
    const float* x2 = x1 + (size_t)TT * HW;
    float* op = out + (size_t)b * (68 * (size_t)HW) + hw;

    op[0] = 0.f; op[HW] = 0.f; op[2 * (size_t)HW] = 0.f; op[3 * (size_t)HW] = 0.f;
    op += 4 * (size_t)HW;

    float a0 = x0[0], a1 = x0[HW], a2 = x0[2*HW], a3 = x0[3*HW], a4 = x0[4*HW];
    float b0 = x1[0], b1 = x1[HW], b2 = x1[2*HW], b3 = x1[3*HW], b4 = x1[4*HW];
    float c0 = x2[0], c1 = x2[HW], c2 = x2[2*HW], c3 = x2[3*HW], c4 = x2[4*HW];

    auto emit = [&](int t, float ra, float rb, float rc) {
        float gsv = 0.2989f * gelu_erf(ra) + 0.587f * gelu_erf(rb) + 0.114f * gelu_erf(rc);
        op[(size_t)t * HW] = fmaf(gsv, sA[t], sB[t]);
    };

    for (int t = 0; t < 59; ++t) {
        emit(t, 4.f*(a4-a0) + 2.f*(a3-a1), 4.f*(b4-b0) + 2.f*(b3-b1), 4.f*(c4-c0) + 2.f*(c3-c1));
        a0=a1; a1=a2; a2=a3; a3=a4; a4 = x0[(size_t)(t+5)*HW];
        b0=b1; b1=b2; b2=b3; b3=b4; b4 = x1[(size_t)(t+5)*HW];
        c0=c1; c1=c2; c2=c3; c3=c4; c4 = x2[(size_t)(t+5)*HW];
    }
    emit(59, 4.f*(a4-a0) + 2.f*(a3-a1), 4.f*(b4-b0) + 2.f*(b3-b1), 4.f*(c4-c0) + 2.f*(c3-c1));
    a0=a1; a1=a2; a2=a3; a3=a4; b0=b1; b1=b2; b2=b3; b3=b4; c0=c1; c1=c2; c2=c3; c3=c4;
    emit(60, 3.f*(a3-a0) + (a2-a1), 3.f*(b3-b0) + (b2-b1), 3.f*(c3-c0) + (c2-c1));
    a0=a1; a1=a2; a2=a3; b0=b1; b1=b2; b2=b3; c0=c1; c1=c2; c2=c3;
    emit(61, 2.f*(a2-a0), 2.f*(b2-b0), 2.f*(c2-c0));
    a0=a1; a1=a2; b0=b1; b1=b2; c0=c1; c1=c2;
    emit(62, a1-a0, b1-b0, c1-c0);
    op[63 * (size_t)HW] = sB[63];
}

extern "C" void kernel_launch(void* const* d_in, const int* in_sizes, int n_in,
                              void* d_out, int out_size, void* d_ws, size_t ws_size,
                              hipStream_t stream) {
    const float* x = (const float*)d_in[0];
    float* out = (float*)d_out;
    // ws layout: [0,1024): ab (fallback); [1024, +802816): part; then gs (~51.4MB)
    float* ab = (float*)d_ws;
    unsigned* part = (unsigned*)((char*)d_ws + 1024);
    const size_t part_bytes = (size_t)2 * TT * NBP * 4;           // 802816
    unsigned* gs = (unsigned*)((char*)d_ws + 1024 + part_bytes);
    const size_t need = 1024 + part_bytes + (size_t)8 * TT * (size_t)HW2 * 4;  // ~52.2 MB

    if (ws_size >= need) {
        k_pass1<true><<<NBP, 128, 0, stream>>>(x, part, gs);
        k_pass3<<<3808, 256, 0, stream>>>(gs, part, out);
    } else if (ws_size >= 1024 + part_bytes) {
        k_pass1<false><<<NBP, 128, 0, stream>>>(x, part, nullptr);
        k_consts<<<TT, 256, 0, stream>>>(part, ab);
        k_pass2_direct<<<1568, 256, 0, stream>>>(x, ab, out);
    }
}